// Round 1
// baseline (944.488 us; speedup 1.0000x reference)
//
#include <hip/hip_runtime.h>

typedef __attribute__((ext_vector_type(8))) short bf16x8;
typedef __attribute__((ext_vector_type(4))) float f32x4;

#define MFMA16(a, b, c) __builtin_amdgcn_mfma_f32_16x16x32_bf16((a), (b), (c), 0, 0, 0)

__device__ inline ushort f2bf(float f) {
    union { float f; unsigned u; } a; a.f = f;
    unsigned r = a.u + 0x7fffu + ((a.u >> 16) & 1u);
    return (ushort)(r >> 16);
}
__device__ inline float bf2f(ushort h) {
    union { unsigned u; float f; } a; a.u = ((unsigned)h) << 16;
    return a.f;
}

// ---------------------------------------------------------------------------
// K1: GroupNorm  x[b,c,t,hw] -> A[(n*16+t)][c] bf16   (n = b*1024+hw)
// grid (64, 32) : blockIdx.x = 64-n chunk, blockIdx.y = group
// ---------------------------------------------------------------------------
__global__ __launch_bounds__(256) void k_groupnorm(
    const float* __restrict__ x, const float* __restrict__ gamma,
    const float* __restrict__ beta, ushort* __restrict__ A) {
    __shared__ float red_s[4][64], red_q[4][64];
    __shared__ float sm_mean[64], sm_rstd[64];
    int tid = threadIdx.x;
    int nb = blockIdx.x, g = blockIdx.y;
    int n_base = nb * 64;
    int b_idx = n_base >> 10;
    int hw_base = n_base & 1023;
    int n_loc = tid & 63, w = tid >> 6;

    // pass 1: per-(n,group) mean/var. element k = c_loc*16 + t, offset k*1024
    const float* xb = x + (size_t)(b_idx * 512 + g * 16) * 16 * 1024 + hw_base + n_loc;
    float s = 0.f, sq = 0.f;
    #pragma unroll 4
    for (int i = 0; i < 64; ++i) {
        int k = w + 4 * i;
        float v = xb[(size_t)k * 1024];
        s += v; sq += v * v;
    }
    red_s[w][n_loc] = s; red_q[w][n_loc] = sq;
    __syncthreads();
    if (tid < 64) {
        float ts = red_s[0][tid] + red_s[1][tid] + red_s[2][tid] + red_s[3][tid];
        float tq = red_q[0][tid] + red_q[1][tid] + red_q[2][tid] + red_q[3][tid];
        float mean = ts * (1.f / 256.f);
        float var = tq * (1.f / 256.f) - mean * mean;
        sm_mean[tid] = mean;
        sm_rstd[tid] = rsqrtf(var + 1e-6f);
    }
    __syncthreads();

    // pass 2: remapped threads -> one (n,t) row of 16 channels each
    #pragma unroll
    for (int it = 0; it < 4; ++it) {
        int row = it * 256 + tid;
        int nl = row >> 4, t2 = row & 15;
        float mean = sm_mean[nl], rstd = sm_rstd[nl];
        const float* xs = x + ((size_t)(b_idx * 512 + g * 16) * 16 + t2) * 1024 + hw_base + nl;
        union { ushort u[16]; uint4 v[2]; } pk;
        #pragma unroll
        for (int cc = 0; cc < 16; ++cc) {
            float v = xs[(size_t)cc * 16 * 1024];
            float y = (v - mean) * rstd * gamma[g * 16 + cc] + beta[g * 16 + cc];
            pk.u[cc] = f2bf(y);
        }
        ushort* dst = A + ((size_t)(n_base + nl) * 16 + t2) * 512 + g * 16;
        ((uint4*)dst)[0] = pk.v[0];
        ((uint4*)dst)[1] = pk.v[1];
    }
}

// ---------------------------------------------------------------------------
// K2/K4: GEMM  C[m][o] = sum_c A[m][c] * W[o][c] + bias[o]   (bf16 out)
// A bf16 [M][512], W fp32 [Nn][512], 128x128x32 tiles, 4 waves (2x2 of 64x64)
// ---------------------------------------------------------------------------
__global__ __launch_bounds__(256) void k_gemm(
    const ushort* __restrict__ Abf, const float* __restrict__ Wf,
    const float* __restrict__ bias, ushort* __restrict__ Cbf, int Nn) {
    __shared__ ushort aT[128 * 32];
    __shared__ ushort bT[128 * 32];
    int tid = threadIdx.x, lane = tid & 63, wv = tid >> 6;
    int wm = wv >> 1, wn = wv & 1;
    int l15 = lane & 15, g4 = lane >> 4;
    size_t m0 = (size_t)blockIdx.x * 128;
    int n0 = blockIdx.y * 128;
    f32x4 acc[4][4];
    #pragma unroll
    for (int i = 0; i < 4; ++i)
        #pragma unroll
        for (int j = 0; j < 4; ++j) acc[i][j] = (f32x4){0.f, 0.f, 0.f, 0.f};

    int q0 = (tid & 3) * 8;       // A staging: k offset (shorts)
    int ob = tid >> 1;            // B staging: row
    int half = (tid & 1) * 16;    // B staging: k offset (floats->shorts)

    for (int kk = 0; kk < 512; kk += 32) {
        __syncthreads();
        // stage A (bf16 16B per thread x2)
        #pragma unroll
        for (int p = 0; p < 2; ++p) {
            int r = p * 64 + (tid >> 2);
            uint4 av = *(const uint4*)(Abf + (m0 + r) * 512 + kk + q0);
            *(uint4*)(&aT[r * 32 + q0]) = av;
        }
        // stage B: fp32 -> bf16 convert
        {
            const float* src = Wf + (size_t)(n0 + ob) * 512 + kk + half;
            float4 f0 = ((const float4*)src)[0];
            float4 f1 = ((const float4*)src)[1];
            float4 f2 = ((const float4*)src)[2];
            float4 f3 = ((const float4*)src)[3];
            union { ushort u[8]; uint4 v; } p0, p1;
            p0.u[0] = f2bf(f0.x); p0.u[1] = f2bf(f0.y); p0.u[2] = f2bf(f0.z); p0.u[3] = f2bf(f0.w);
            p0.u[4] = f2bf(f1.x); p0.u[5] = f2bf(f1.y); p0.u[6] = f2bf(f1.z); p0.u[7] = f2bf(f1.w);
            p1.u[0] = f2bf(f2.x); p1.u[1] = f2bf(f2.y); p1.u[2] = f2bf(f2.z); p1.u[3] = f2bf(f2.w);
            p1.u[4] = f2bf(f3.x); p1.u[5] = f2bf(f3.y); p1.u[6] = f2bf(f3.z); p1.u[7] = f2bf(f3.w);
            *(uint4*)(&bT[ob * 32 + half]) = p0.v;
            *(uint4*)(&bT[ob * 32 + half + 8]) = p1.v;
        }
        __syncthreads();
        bf16x8 af[4], bfr[4];
        #pragma unroll
        for (int i = 0; i < 4; ++i) {
            af[i]  = *(const bf16x8*)(&aT[(wm * 64 + i * 16 + l15) * 32 + g4 * 8]);
            bfr[i] = *(const bf16x8*)(&bT[(wn * 64 + i * 16 + l15) * 32 + g4 * 8]);
        }
        #pragma unroll
        for (int i = 0; i < 4; ++i)
            #pragma unroll
            for (int j = 0; j < 4; ++j)
                acc[i][j] = MFMA16(af[i], bfr[j], acc[i][j]);
    }
    // epilogue: bias + bf16 store
    #pragma unroll
    for (int j = 0; j < 4; ++j) {
        int col = n0 + wn * 64 + j * 16 + l15;
        float bi = bias[col];
        #pragma unroll
        for (int i = 0; i < 4; ++i) {
            size_t rowb = m0 + wm * 64 + i * 16 + g4 * 4;
            #pragma unroll
            for (int r = 0; r < 4; ++r)
                Cbf[(rowb + r) * (size_t)Nn + col] = f2bf(acc[i][j][r] + bi);
        }
    }
}

// ---------------------------------------------------------------------------
// K3: attention per (n, head). 2 waves/block, 1 wave = 1 (n,head).
// q,k,v bf16 [64ch x 16t] from C1 rows (n*16+t), cols {0,512,1024}+head*64.
// w[i][j] = 0.125*(q.k) + scale*P[i-j+15][j],  P[d][j]=sum_c rpk[d][c] q[c][j]
// out[i][c] = sum_j w[i][j] v[c][j] + sum_d W2[i][d] rpv[d][c],
//   W2[i][d] = w[i][i+d-15]
// ---------------------------------------------------------------------------
__global__ __launch_bounds__(128) void k_attn(
    const ushort* __restrict__ C1, const float* __restrict__ rp_k,
    const float* __restrict__ rp_v, ushort* __restrict__ O) {
    __shared__ ushort rpk_s[32 * 64];    // [d][c], d=31 zero
    __shared__ ushort rpvT_s[64 * 32];   // [c][d], d=31 zero
    __shared__ ushort q_s[2][16 * 64];   // [t][c]
    __shared__ ushort k_s[2][16 * 64];   // [t][c]
    __shared__ ushort v2_s[2][64 * 32];  // [c][t], t=16..31 zero
    __shared__ ushort wbf_s[2][16 * 32]; // [i][j], j=16..31 zero
    __shared__ ushort w2_s[2][16 * 32];  // [i][d]
    __shared__ float  pa_s[2][32 * 17];  // [d][j] padded
    __shared__ float  a_s[2][16 * 69];   // [i][c] padded

    int tid = threadIdx.x, lane = tid & 63, wv = tid >> 6;
    // build rel-pos tables (block-cooperative)
    for (int q = 0; q < 16; ++q) {
        int e = tid * 16 + q;
        int d = e >> 6, c = e & 63;
        rpk_s[e] = (d < 31) ? f2bf(rp_k[(size_t)(49 + d) * 64 + c]) : (ushort)0;
        int c2 = e >> 5, d2 = e & 31;
        rpvT_s[e] = (d2 < 31) ? f2bf(rp_v[(size_t)(49 + d2) * 64 + c2]) : (ushort)0;
    }
    __syncthreads();

    int bh = blockIdx.x * 2 + wv;
    int n = bh >> 3, head = bh & 7;
    const ushort* base = C1 + (size_t)n * 16 * 1536 + head * 64;
    ushort* qp = q_s[wv]; ushort* kp = k_s[wv]; ushort* vp = v2_s[wv];
    #pragma unroll
    for (int t = 0; t < 16; ++t) {
        qp[t * 64 + lane] = base[(size_t)t * 1536 + lane];
        kp[t * 64 + lane] = base[(size_t)t * 1536 + 512 + lane];
        vp[lane * 32 + t] = base[(size_t)t * 1536 + 1024 + lane];
    }
    { uint4 z = {0, 0, 0, 0};
      *(uint4*)(&vp[lane * 32 + 16]) = z;
      *(uint4*)(&vp[lane * 32 + 24]) = z; }

    int l15 = lane & 15, g4 = lane >> 4;
    bf16x8 qf0 = *(const bf16x8*)(&qp[l15 * 64 + g4 * 8]);
    bf16x8 qf1 = *(const bf16x8*)(&qp[l15 * 64 + 32 + g4 * 8]);
    bf16x8 kf0 = *(const bf16x8*)(&kp[l15 * 64 + g4 * 8]);
    bf16x8 kf1 = *(const bf16x8*)(&kp[l15 * 64 + 32 + g4 * 8]);
    f32x4 zero = {0.f, 0.f, 0.f, 0.f};
    f32x4 wc = MFMA16(qf0, kf0, zero);
    wc = MFMA16(qf1, kf1, wc);
    // P = rpk_local @ q   (rows d, cols j)
    f32x4 P0, P1;
    {
        bf16x8 rk;
        rk = *(const bf16x8*)(&rpk_s[l15 * 64 + g4 * 8]);            P0 = MFMA16(rk, qf0, zero);
        rk = *(const bf16x8*)(&rpk_s[l15 * 64 + 32 + g4 * 8]);       P0 = MFMA16(rk, qf1, P0);
        rk = *(const bf16x8*)(&rpk_s[(16 + l15) * 64 + g4 * 8]);     P1 = MFMA16(rk, qf0, zero);
        rk = *(const bf16x8*)(&rpk_s[(16 + l15) * 64 + 32 + g4 * 8]);P1 = MFMA16(rk, qf1, P1);
    }
    float* pa = pa_s[wv];
    #pragma unroll
    for (int r = 0; r < 4; ++r) {
        pa[(g4 * 4 + r) * 17 + l15] = P0[r];
        pa[(16 + g4 * 4 + r) * 17 + l15] = P1[r];
    }
    // scores + softmax (row i across 16-lane groups)
    ushort* wb = wbf_s[wv];
    #pragma unroll
    for (int r = 0; r < 4; ++r) {
        int i = g4 * 4 + r;
        float sc = 0.125f * wc[r] + 0.35355339059327373f * pa[(i - l15 + 15) * 17 + l15];
        float mx = sc;
        mx = fmaxf(mx, __shfl_xor(mx, 1));
        mx = fmaxf(mx, __shfl_xor(mx, 2));
        mx = fmaxf(mx, __shfl_xor(mx, 4));
        mx = fmaxf(mx, __shfl_xor(mx, 8));
        float e = __expf(sc - mx);
        float sm = e;
        sm += __shfl_xor(sm, 1); sm += __shfl_xor(sm, 2);
        sm += __shfl_xor(sm, 4); sm += __shfl_xor(sm, 8);
        float p = e / sm;
        wb[i * 32 + l15] = f2bf(p);
        wb[i * 32 + 16 + l15] = 0;
    }
    // W2[i][d] = w[i][i+d-15]
    ushort* w2 = w2_s[wv];
    #pragma unroll
    for (int q = 0; q < 8; ++q) {
        int e = lane * 8 + q;
        int i = e >> 5, d = e & 31;
        int j = i + d - 15;
        ushort val = 0;
        if (d < 31 && j >= 0 && j < 16) val = wb[i * 32 + j];
        w2[e] = val;
    }
    // PV main: D[c][i] = sum_j v[c][j] w[i][j]
    bf16x8 wfr = *(const bf16x8*)(&wb[l15 * 32 + g4 * 8]);
    float* as_ = a_s[wv];
    #pragma unroll
    for (int mi = 0; mi < 4; ++mi) {
        bf16x8 vf = *(const bf16x8*)(&vp[(mi * 16 + l15) * 32 + g4 * 8]);
        f32x4 av = MFMA16(vf, wfr, zero);
        #pragma unroll
        for (int r = 0; r < 4; ++r)
            as_[l15 * 69 + mi * 16 + g4 * 4 + r] = av[r];
    }
    // rel-V: D[i][c] = sum_d W2[i][d] rpvT[c][d]
    bf16x8 w2f = *(const bf16x8*)(&w2[l15 * 32 + g4 * 8]);
    #pragma unroll
    for (int cj = 0; cj < 4; ++cj) {
        bf16x8 rvf = *(const bf16x8*)(&rpvT_s[(cj * 16 + l15) * 32 + g4 * 8]);
        f32x4 av = MFMA16(w2f, rvf, zero);
        #pragma unroll
        for (int r = 0; r < 4; ++r)
            as_[(g4 * 4 + r) * 69 + cj * 16 + l15] += av[r];
    }
    // store bf16
    ushort* ob = O + (size_t)n * 16 * 512 + head * 64;
    #pragma unroll
    for (int t = 0; t < 16; ++t)
        ob[(size_t)t * 512 + lane] = f2bf(as_[t * 69 + lane]);
}

// ---------------------------------------------------------------------------
// K5: out[b,c,t,hw] = x[b,c,t,hw] + C2[(b*1024+hw)*16+t][c]
// block: 64 hw x 64 c for fixed (b,t); LDS transpose
// ---------------------------------------------------------------------------
__global__ __launch_bounds__(256) void k_out(
    const ushort* __restrict__ C2, const float* __restrict__ x,
    float* __restrict__ out) {
    __shared__ ushort tile[64 * 74];
    int tid = threadIdx.x;
    int idx = blockIdx.x;
    int hw0 = (idx & 15) * 64;
    int c0 = ((idx >> 4) & 7) * 64;
    int t = (idx >> 7) & 15;
    int b = idx >> 11;
    #pragma unroll
    for (int p = 0; p < 2; ++p) {
        int hw_l = p * 32 + (tid >> 3);
        int c8 = (tid & 7) * 8;
        size_t m = (size_t)(b * 1024 + hw0 + hw_l) * 16 + t;
        union { uint4 v; ushort u[8]; } un;
        un.v = *(const uint4*)(C2 + m * 512 + c0 + c8);
        #pragma unroll
        for (int q = 0; q < 8; ++q) tile[hw_l * 74 + c8 + q] = un.u[q];
    }
    __syncthreads();
    #pragma unroll
    for (int it = 0; it < 16; ++it) {
        int flat = it * 256 + tid;
        int c_l = flat >> 6, hw_l = flat & 63;
        float v = bf2f(tile[hw_l * 74 + c_l]);
        size_t oi = ((size_t)(b * 512 + c0 + c_l) * 16 + t) * 1024 + hw0 + hw_l;
        out[oi] = x[oi] + v;
    }
}

// ---------------------------------------------------------------------------
extern "C" void kernel_launch(void* const* d_in, const int* in_sizes, int n_in,
                              void* d_out, int out_size, void* d_ws, size_t ws_size,
                              hipStream_t stream) {
    const float* x      = (const float*)d_in[0];
    const float* gamma  = (const float*)d_in[1];
    const float* beta   = (const float*)d_in[2];
    const float* w_qkv  = (const float*)d_in[3];
    const float* b_qkv  = (const float*)d_in[4];
    const float* rp_k   = (const float*)d_in[5];
    const float* rp_v   = (const float*)d_in[6];
    const float* w_proj = (const float*)d_in[7];
    const float* b_proj = (const float*)d_in[8];
    float* out = (float*)d_out;

    ushort* A  = (ushort*)d_ws;                       // 64 MB: normed, later attn-out
    ushort* C1 = A + (size_t)32 * 1024 * 1024;        // 192 MB: qkv, later C2 (64MB)
    ushort* C2 = C1;

    k_groupnorm<<<dim3(64, 32), dim3(256), 0, stream>>>(x, gamma, beta, A);
    k_gemm<<<dim3(512, 12), dim3(256), 0, stream>>>(A, w_qkv, b_qkv, C1, 1536);
    k_attn<<<dim3(16384), dim3(128), 0, stream>>>(C1, rp_k, rp_v, A);
    k_gemm<<<dim3(512, 4), dim3(256), 0, stream>>>(A, w_proj, b_proj, C2, 512);
    k_out<<<dim3(8192), dim3(256), 0, stream>>>(C2, x, out);
}

// Round 2
// 689.804 us; speedup vs baseline: 1.3692x; 1.3692x over previous
//
#include <hip/hip_runtime.h>

typedef __attribute__((ext_vector_type(8))) short bf16x8;
typedef __attribute__((ext_vector_type(4))) float f32x4;

#define MFMA16(a, b, c) __builtin_amdgcn_mfma_f32_16x16x32_bf16((a), (b), (c), 0, 0, 0)

__device__ inline ushort f2bf(float f) {
    union { float f; unsigned u; } a; a.f = f;
    unsigned r = a.u + 0x7fffu + ((a.u >> 16) & 1u);
    return (ushort)(r >> 16);
}
__device__ inline float bf2f(ushort h) {
    union { unsigned u; float f; } a; a.u = ((unsigned)h) << 16;
    return a.f;
}
__device__ inline void gload_lds16(const void* g, void* l) {
    __builtin_amdgcn_global_load_lds((const __attribute__((address_space(1))) unsigned*)g,
                                     (__attribute__((address_space(3))) unsigned*)l, 16, 0, 0);
}

// ---------------------------------------------------------------------------
// K0: convert w_qkv (1536x512) and w_proj (512x512) fp32 -> bf16 into scratch
// ---------------------------------------------------------------------------
__global__ __launch_bounds__(256) void k_convw(
    const float* __restrict__ wq, const float* __restrict__ wp,
    ushort* __restrict__ dst) {
    size_t e = ((size_t)blockIdx.x * 256 + threadIdx.x) * 4;   // grid 1024 -> 4M elems/4
    float4 v;
    if (e < 786432) v = *(const float4*)(wq + e);
    else            v = *(const float4*)(wp + (e - 786432));
    ushort4 o;
    o.x = f2bf(v.x); o.y = f2bf(v.y); o.z = f2bf(v.z); o.w = f2bf(v.w);
    *(ushort4*)(dst + e) = o;
}

// ---------------------------------------------------------------------------
// K1: GroupNorm  x[b,c,t,hw] -> A[(n*16+t)][c] bf16   (n = b*1024+hw)
// ---------------------------------------------------------------------------
__global__ __launch_bounds__(256) void k_groupnorm(
    const float* __restrict__ x, const float* __restrict__ gamma,
    const float* __restrict__ beta, ushort* __restrict__ A) {
    __shared__ float red_s[4][64], red_q[4][64];
    __shared__ float sm_mean[64], sm_rstd[64];
    int tid = threadIdx.x;
    int nb = blockIdx.x, g = blockIdx.y;
    int n_base = nb * 64;
    int b_idx = n_base >> 10;
    int hw_base = n_base & 1023;
    int n_loc = tid & 63, w = tid >> 6;

    // pass 1: per-(n,group) mean/var
    const float* xb = x + (size_t)(b_idx * 512 + g * 16) * 16 * 1024 + hw_base + n_loc;
    float s = 0.f, sq = 0.f;
    #pragma unroll 4
    for (int i = 0; i < 64; ++i) {
        int k = w + 4 * i;
        float v = xb[(size_t)k * 1024];
        s += v; sq += v * v;
    }
    red_s[w][n_loc] = s; red_q[w][n_loc] = sq;
    __syncthreads();
    if (tid < 64) {
        float ts = red_s[0][tid] + red_s[1][tid] + red_s[2][tid] + red_s[3][tid];
        float tq = red_q[0][tid] + red_q[1][tid] + red_q[2][tid] + red_q[3][tid];
        float mean = ts * (1.f / 256.f);
        float var = tq * (1.f / 256.f) - mean * mean;
        sm_mean[tid] = mean;
        sm_rstd[tid] = rsqrtf(var + 1e-6f);
    }
    __syncthreads();

    // pass 2: coalesced — 64 consecutive lanes read 64 consecutive hw
    int nl = tid & 63;
    float mean = sm_mean[nl], rstd = sm_rstd[nl];
    #pragma unroll
    for (int it = 0; it < 4; ++it) {
        int t2 = it * 4 + (tid >> 6);
        const float* xs = x + ((size_t)(b_idx * 512 + g * 16) * 16 + t2) * 1024 + hw_base + nl;
        union { ushort u[16]; uint4 v[2]; } pk;
        #pragma unroll
        for (int cc = 0; cc < 16; ++cc) {
            float v = xs[(size_t)cc * 16 * 1024];
            float y = (v - mean) * rstd * gamma[g * 16 + cc] + beta[g * 16 + cc];
            pk.u[cc] = f2bf(y);
        }
        ushort* dst = A + ((size_t)(n_base + nl) * 16 + t2) * 512 + g * 16;
        ((uint4*)dst)[0] = pk.v[0];
        ((uint4*)dst)[1] = pk.v[1];
    }
}

// ---------------------------------------------------------------------------
// K2/K4: GEMM  C[m][o] = sum_c A[m][c]*W[o][c] + bias[o]  (all bf16, m97-style)
// grid (Nn/128, M/128): n fastest for A-panel L2 reuse
// ---------------------------------------------------------------------------
__global__ __launch_bounds__(256) void k_gemm(
    const ushort* __restrict__ Abf, const ushort* __restrict__ Wbf,
    const float* __restrict__ bias, ushort* __restrict__ Cbf, int Nn) {
    __shared__ ushort aT[128 * 32];
    __shared__ ushort bT[128 * 32];
    int tid = threadIdx.x, lane = tid & 63, wv = tid >> 6;
    int wm = wv >> 1, wn = wv & 1;
    int l15 = lane & 15, g4 = lane >> 4;
    int n0 = blockIdx.x * 128;
    size_t m0 = (size_t)blockIdx.y * 128;
    f32x4 acc[4][4];
    #pragma unroll
    for (int i = 0; i < 4; ++i)
        #pragma unroll
        for (int j = 0; j < 4; ++j) acc[i][j] = (f32x4){0.f, 0.f, 0.f, 0.f};

    // staging address bases: chunk = 16 rows; wave stages 1024B per gload
    int rowA = lane >> 2;            // row within 16-row chunk
    int kcol = (lane & 3) * 8;       // k slot (shorts)
    const ushort* Ab = Abf + (m0 + rowA) * 512 + kcol;
    const ushort* Bb = Wbf + (size_t)(n0 + rowA) * 512 + kcol;

    for (int kk = 0; kk < 512; kk += 32) {
        if (kk) __syncthreads();
        #pragma unroll
        for (int r = 0; r < 2; ++r) {
            int rb = (r * 4 + wv) * 16;                  // wave-uniform chunk base row
            gload_lds16(Ab + (size_t)rb * 512 + kk, &aT[rb * 32]);
            gload_lds16(Bb + (size_t)rb * 512 + kk, &bT[rb * 32]);
        }
        __syncthreads();
        bf16x8 af[4], bfr[4];
        #pragma unroll
        for (int i = 0; i < 4; ++i) {
            af[i]  = *(const bf16x8*)(&aT[(wm * 64 + i * 16 + l15) * 32 + g4 * 8]);
            bfr[i] = *(const bf16x8*)(&bT[(wn * 64 + i * 16 + l15) * 32 + g4 * 8]);
        }
        #pragma unroll
        for (int i = 0; i < 4; ++i)
            #pragma unroll
            for (int j = 0; j < 4; ++j)
                acc[i][j] = MFMA16(af[i], bfr[j], acc[i][j]);
    }
    // epilogue: bias + bf16 store
    #pragma unroll
    for (int j = 0; j < 4; ++j) {
        int col = n0 + wn * 64 + j * 16 + l15;
        float bi = bias[col];
        #pragma unroll
        for (int i = 0; i < 4; ++i) {
            size_t rowb = m0 + wm * 64 + i * 16 + g4 * 4;
            #pragma unroll
            for (int r = 0; r < 4; ++r)
                Cbf[(rowb + r) * (size_t)Nn + col] = f2bf(acc[i][j][r] + bi);
        }
    }
}

// ---------------------------------------------------------------------------
// K3: attention per (n, head). 2 waves/block, 1 wave = 1 (n,head).
// w[i][j] = 0.125*(q.k) + scale*P[i-j+15][j],  P[d][j]=sum_c rpk[d][c] q[c][j]
// out[i][c] = sum_j w[i][j] v[c][j] + sum_d W2[i][d] rpv[d][c], W2[i][d]=w[i][i+d-15]
// ---------------------------------------------------------------------------
__global__ __launch_bounds__(128) void k_attn(
    const ushort* __restrict__ C1, const float* __restrict__ rp_k,
    const float* __restrict__ rp_v, ushort* __restrict__ O) {
    __shared__ ushort rpk_s[32 * 64];    // [d][c], d=31 zero
    __shared__ ushort rpvT_s[64 * 32];   // [c][d], d=31 zero
    __shared__ ushort q_s[2][16 * 64];   // [t][c]
    __shared__ ushort k_s[2][16 * 64];   // [t][c]
    __shared__ ushort v2_s[2][64 * 32];  // [c][t], t=16..31 zero
    __shared__ ushort wbf_s[2][16 * 32]; // [i][j], j=16..31 zero
    __shared__ ushort w2_s[2][16 * 32];  // [i][d]
    __shared__ float  pa_s[2][32 * 17];  // [d][j] padded

    int tid = threadIdx.x, lane = tid & 63, wv = tid >> 6;
    // rel-pos tables (block-cooperative)
    for (int q = 0; q < 16; ++q) {
        int e = tid * 16 + q;
        int d = e >> 6, c = e & 63;
        rpk_s[e] = (d < 31) ? f2bf(rp_k[(size_t)(49 + d) * 64 + c]) : (ushort)0;
        int c2 = e >> 5, d2 = e & 31;
        rpvT_s[e] = (d2 < 31) ? f2bf(rp_v[(size_t)(49 + d2) * 64 + c2]) : (ushort)0;
    }
    __syncthreads();

    int bh = blockIdx.x * 2 + wv;
    int n = bh >> 3, head = bh & 7;
    const ushort* base = C1 + (size_t)n * 16 * 1536 + head * 64;
    ushort* qp = q_s[wv]; ushort* kp = k_s[wv]; ushort* vp = v2_s[wv];
    // vectorized staging: 8 lanes cover one row's 64 ch (128B)
    int t8 = lane >> 3, c8 = (lane & 7) * 8;
    #pragma unroll
    for (int p = 0; p < 2; ++p) {
        int t = p * 8 + t8;
        const ushort* rb = base + (size_t)t * 1536;
        *(uint4*)(&qp[t * 64 + c8]) = *(const uint4*)(rb + c8);
        *(uint4*)(&kp[t * 64 + c8]) = *(const uint4*)(rb + 512 + c8);
        uint4 vvv = *(const uint4*)(rb + 1024 + c8);
        const ushort* vu = (const ushort*)&vvv;
        #pragma unroll
        for (int qq = 0; qq < 8; ++qq) vp[(c8 + qq) * 32 + t] = vu[qq];
    }
    { uint4 z = {0, 0, 0, 0};
      *(uint4*)(&vp[lane * 32 + 16]) = z;
      *(uint4*)(&vp[lane * 32 + 24]) = z; }

    int l15 = lane & 15, g4 = lane >> 4;
    bf16x8 qf0 = *(const bf16x8*)(&qp[l15 * 64 + g4 * 8]);
    bf16x8 qf1 = *(const bf16x8*)(&qp[l15 * 64 + 32 + g4 * 8]);
    bf16x8 kf0 = *(const bf16x8*)(&kp[l15 * 64 + g4 * 8]);
    bf16x8 kf1 = *(const bf16x8*)(&kp[l15 * 64 + 32 + g4 * 8]);
    f32x4 zero = {0.f, 0.f, 0.f, 0.f};
    f32x4 wc = MFMA16(qf0, kf0, zero);
    wc = MFMA16(qf1, kf1, wc);
    // P = rpk @ q   (rows d, cols j)
    f32x4 P0, P1;
    {
        bf16x8 rk;
        rk = *(const bf16x8*)(&rpk_s[l15 * 64 + g4 * 8]);             P0 = MFMA16(rk, qf0, zero);
        rk = *(const bf16x8*)(&rpk_s[l15 * 64 + 32 + g4 * 8]);        P0 = MFMA16(rk, qf1, P0);
        rk = *(const bf16x8*)(&rpk_s[(16 + l15) * 64 + g4 * 8]);      P1 = MFMA16(rk, qf0, zero);
        rk = *(const bf16x8*)(&rpk_s[(16 + l15) * 64 + 32 + g4 * 8]); P1 = MFMA16(rk, qf1, P1);
    }
    float* pa = pa_s[wv];
    #pragma unroll
    for (int r = 0; r < 4; ++r) {
        pa[(g4 * 4 + r) * 17 + l15] = P0[r];
        pa[(16 + g4 * 4 + r) * 17 + l15] = P1[r];
    }
    // scores + softmax (row i across 16-lane groups)
    ushort* wb = wbf_s[wv];
    #pragma unroll
    for (int r = 0; r < 4; ++r) {
        int i = g4 * 4 + r;
        float sc = 0.125f * wc[r] + 0.35355339059327373f * pa[(i - l15 + 15) * 17 + l15];
        float mx = sc;
        mx = fmaxf(mx, __shfl_xor(mx, 1));
        mx = fmaxf(mx, __shfl_xor(mx, 2));
        mx = fmaxf(mx, __shfl_xor(mx, 4));
        mx = fmaxf(mx, __shfl_xor(mx, 8));
        float e = __expf(sc - mx);
        float sm = e;
        sm += __shfl_xor(sm, 1); sm += __shfl_xor(sm, 2);
        sm += __shfl_xor(sm, 4); sm += __shfl_xor(sm, 8);
        float p = e / sm;
        wb[i * 32 + l15] = f2bf(p);
        wb[i * 32 + 16 + l15] = 0;
    }
    // W2[i][d] = w[i][i+d-15]
    ushort* w2 = w2_s[wv];
    #pragma unroll
    for (int q = 0; q < 8; ++q) {
        int e = lane * 8 + q;
        int i = e >> 5, d = e & 31;
        int j = i + d - 15;
        ushort val = 0;
        if (d < 31 && j >= 0 && j < 16) val = wb[i * 32 + j];
        w2[e] = val;
    }
    // fused PV + rel-V:  D[i][c] = sum_j w[i][j] v[c][j] + sum_d W2[i][d] rpvT[c][d]
    bf16x8 wfr = *(const bf16x8*)(&wb[l15 * 32 + g4 * 8]);
    bf16x8 w2f = *(const bf16x8*)(&w2[l15 * 32 + g4 * 8]);
    ushort* ob = O + (size_t)n * 16 * 512 + head * 64;
    #pragma unroll
    for (int cj = 0; cj < 4; ++cj) {
        bf16x8 vf  = *(const bf16x8*)(&vp[(cj * 16 + l15) * 32 + g4 * 8]);
        bf16x8 rvf = *(const bf16x8*)(&rpvT_s[(cj * 16 + l15) * 32 + g4 * 8]);
        f32x4 av = MFMA16(wfr, vf, zero);
        av = MFMA16(w2f, rvf, av);
        #pragma unroll
        for (int r = 0; r < 4; ++r)
            ob[(size_t)(g4 * 4 + r) * 512 + cj * 16 + l15] = f2bf(av[r]);
    }
}

// ---------------------------------------------------------------------------
// K5: out[b,c,t,hw] = x[b,c,t,hw] + C2[(b*1024+hw)*16+t][c]
// ---------------------------------------------------------------------------
__global__ __launch_bounds__(256) void k_out(
    const ushort* __restrict__ C2, const float* __restrict__ x,
    float* __restrict__ out) {
    __shared__ ushort tile[64 * 74];
    int tid = threadIdx.x;
    int idx = blockIdx.x;
    int hw0 = (idx & 15) * 64;
    int c0 = ((idx >> 4) & 7) * 64;
    int t = (idx >> 7) & 15;
    int b = idx >> 11;
    #pragma unroll
    for (int p = 0; p < 2; ++p) {
        int hw_l = p * 32 + (tid >> 3);
        int c8 = (tid & 7) * 8;
        size_t m = (size_t)(b * 1024 + hw0 + hw_l) * 16 + t;
        union { uint4 v; ushort u[8]; } un;
        un.v = *(const uint4*)(C2 + m * 512 + c0 + c8);
        #pragma unroll
        for (int q = 0; q < 8; ++q) tile[hw_l * 74 + c8 + q] = un.u[q];
    }
    __syncthreads();
    #pragma unroll
    for (int it = 0; it < 16; ++it) {
        int flat = it * 256 + tid;
        int c_l = flat >> 6, hw_l = flat & 63;
        float v = bf2f(tile[hw_l * 74 + c_l]);
        size_t oi = ((size_t)(b * 512 + c0 + c_l) * 16 + t) * 1024 + hw0 + hw_l;
        out[oi] = x[oi] + v;
    }
}

// ---------------------------------------------------------------------------
extern "C" void kernel_launch(void* const* d_in, const int* in_sizes, int n_in,
                              void* d_out, int out_size, void* d_ws, size_t ws_size,
                              hipStream_t stream) {
    const float* x      = (const float*)d_in[0];
    const float* gamma  = (const float*)d_in[1];
    const float* beta   = (const float*)d_in[2];
    const float* w_qkv  = (const float*)d_in[3];
    const float* b_qkv  = (const float*)d_in[4];
    const float* rp_k   = (const float*)d_in[5];
    const float* rp_v   = (const float*)d_in[6];
    const float* w_proj = (const float*)d_in[7];
    const float* b_proj = (const float*)d_in[8];
    float* out = (float*)d_out;

    ushort* A  = (ushort*)d_ws;                       // 64 MB: normed, later attn-out
    ushort* C1 = A + (size_t)32 * 1024 * 1024;        // 192 MB: qkv, later C2 (64MB)
    ushort* C2 = C1;
    // bf16 weights live in d_out scratch (fully overwritten by k_out at the end)
    ushort* Wq = (ushort*)d_out;
    ushort* Wp = Wq + 1536 * 512;

    k_convw<<<dim3(1024), dim3(256), 0, stream>>>(w_qkv, w_proj, Wq);
    k_groupnorm<<<dim3(64, 32), dim3(256), 0, stream>>>(x, gamma, beta, A);
    k_gemm<<<dim3(12, 512), dim3(256), 0, stream>>>(A, Wq, b_qkv, C1, 1536);
    k_attn<<<dim3(16384), dim3(128), 0, stream>>>(C1, rp_k, rp_v, A);
    k_gemm<<<dim3(4, 512), dim3(256), 0, stream>>>(A, Wp, b_proj, C2, 512);
    k_out<<<dim3(8192), dim3(256), 0, stream>>>(C2, x, out);
}

// Round 3
// 647.303 us; speedup vs baseline: 1.4591x; 1.0657x over previous
//
#include <hip/hip_runtime.h>

typedef __attribute__((ext_vector_type(8))) short bf16x8;
typedef __attribute__((ext_vector_type(4))) float f32x4;

#define MFMA16(a, b, c) __builtin_amdgcn_mfma_f32_16x16x32_bf16((a), (b), (c), 0, 0, 0)

__device__ inline ushort f2bf(float f) {
    union { float f; unsigned u; } a; a.f = f;
    unsigned r = a.u + 0x7fffu + ((a.u >> 16) & 1u);
    return (ushort)(r >> 16);
}
__device__ inline float bf2f(ushort h) {
    union { unsigned u; float f; } a; a.u = ((unsigned)h) << 16;
    return a.f;
}
__device__ inline void gload_lds16(const void* g, void* l) {
    __builtin_amdgcn_global_load_lds((const __attribute__((address_space(1))) unsigned*)g,
                                     (__attribute__((address_space(3))) unsigned*)l, 16, 0, 0);
}

// ---------------------------------------------------------------------------
// K0: fp32->bf16 weights + rel-pos tables into scratch
// blocks 0..1023: weights; block 1024: rp tables
// ---------------------------------------------------------------------------
__global__ __launch_bounds__(256) void k_convw(
    const float* __restrict__ wq, const float* __restrict__ wp,
    const float* __restrict__ rp_k, const float* __restrict__ rp_v,
    ushort* __restrict__ dst) {
    int tid = threadIdx.x;
    if (blockIdx.x < 1024) {
        size_t e = ((size_t)blockIdx.x * 256 + tid) * 4;
        float4 v;
        if (e < 786432) v = *(const float4*)(wq + e);
        else            v = *(const float4*)(wp + (e - 786432));
        ushort4 o;
        o.x = f2bf(v.x); o.y = f2bf(v.y); o.z = f2bf(v.z); o.w = f2bf(v.w);
        *(ushort4*)(dst + e) = o;
    } else {
        ushort* rpk_g  = dst + 1048576;          // [32][64]
        ushort* rpvT_g = rpk_g + 2048;           // [64][32]
        #pragma unroll
        for (int q = 0; q < 8; ++q) {
            int e = tid * 8 + q;
            int d = e >> 6, c = e & 63;
            rpk_g[e] = (d < 31) ? f2bf(rp_k[(size_t)(49 + d) * 64 + c]) : (ushort)0;
            int c2 = e >> 5, d2 = e & 31;
            rpvT_g[e] = (d2 < 31) ? f2bf(rp_v[(size_t)(49 + d2) * 64 + c2]) : (ushort)0;
        }
    }
}

// ---------------------------------------------------------------------------
// K1: GroupNorm  x[b,c,t,hw] -> A[(n*16+t)][c] bf16   (n = b*1024+hw)
// ---------------------------------------------------------------------------
__global__ __launch_bounds__(256) void k_groupnorm(
    const float* __restrict__ x, const float* __restrict__ gamma,
    const float* __restrict__ beta, ushort* __restrict__ A) {
    __shared__ float red_s[4][64], red_q[4][64];
    __shared__ float sm_mean[64], sm_rstd[64];
    int tid = threadIdx.x;
    int nb = blockIdx.x, g = blockIdx.y;
    int n_base = nb * 64;
    int b_idx = n_base >> 10;
    int hw_base = n_base & 1023;
    int n_loc = tid & 63, w = tid >> 6;

    const float* xb = x + (size_t)(b_idx * 512 + g * 16) * 16 * 1024 + hw_base + n_loc;
    float s = 0.f, sq = 0.f;
    #pragma unroll 4
    for (int i = 0; i < 64; ++i) {
        int k = w + 4 * i;
        float v = xb[(size_t)k * 1024];
        s += v; sq += v * v;
    }
    red_s[w][n_loc] = s; red_q[w][n_loc] = sq;
    __syncthreads();
    if (tid < 64) {
        float ts = red_s[0][tid] + red_s[1][tid] + red_s[2][tid] + red_s[3][tid];
        float tq = red_q[0][tid] + red_q[1][tid] + red_q[2][tid] + red_q[3][tid];
        float mean = ts * (1.f / 256.f);
        float var = tq * (1.f / 256.f) - mean * mean;
        sm_mean[tid] = mean;
        sm_rstd[tid] = rsqrtf(var + 1e-6f);
    }
    __syncthreads();

    int nl = tid & 63;
    float mean = sm_mean[nl], rstd = sm_rstd[nl];
    #pragma unroll
    for (int it = 0; it < 4; ++it) {
        int t2 = it * 4 + (tid >> 6);
        const float* xs = x + ((size_t)(b_idx * 512 + g * 16) * 16 + t2) * 1024 + hw_base + nl;
        union { ushort u[16]; uint4 v[2]; } pk;
        #pragma unroll
        for (int cc = 0; cc < 16; ++cc) {
            float v = xs[(size_t)cc * 16 * 1024];
            float y = (v - mean) * rstd * gamma[g * 16 + cc] + beta[g * 16 + cc];
            pk.u[cc] = f2bf(y);
        }
        ushort* dst = A + ((size_t)(n_base + nl) * 16 + t2) * 512 + g * 16;
        ((uint4*)dst)[0] = pk.v[0];
        ((uint4*)dst)[1] = pk.v[1];
    }
}

// ---------------------------------------------------------------------------
// K2/K4: GEMM  C[m][o] = sum_c A[m][c]*W[o][c] + bias[o]  (bf16)
// 1-D grid, XCD-partitioned: xcd = wg&7 owns m-panels [xcd*mpx, (xcd+1)*mpx),
// n fastest within XCD -> A panel HBM-fetched once per XCD.
// 2-phase prefetch: dbuf LDS, stage(t+1) issued before compute(t).
// ---------------------------------------------------------------------------
__global__ __launch_bounds__(256) void k_gemm(
    const ushort* __restrict__ Abf, const ushort* __restrict__ Wbf,
    const float* __restrict__ bias, ushort* __restrict__ Cbf,
    int Nn, int nb, int mpx) {
    __shared__ ushort aT[2][128 * 32];
    __shared__ ushort bT[2][128 * 32];
    int tid = threadIdx.x, lane = tid & 63, wv = tid >> 6;
    int wm = wv >> 1, wn = wv & 1;
    int l15 = lane & 15, g4 = lane >> 4;
    int wg = blockIdx.x;
    int xcd = wg & 7, idx = wg >> 3;
    int mp = xcd * mpx + idx / nb;
    int np = idx % nb;
    size_t m0 = (size_t)mp * 128;
    int n0 = np * 128;

    f32x4 acc[4][4];
    #pragma unroll
    for (int i = 0; i < 4; ++i)
        #pragma unroll
        for (int j = 0; j < 4; ++j) acc[i][j] = (f32x4){0.f, 0.f, 0.f, 0.f};

    int rowA = lane >> 2;
    int kcol = (lane & 3) * 8;
    const ushort* Ab = Abf + (m0 + rowA) * 512 + kcol;
    const ushort* Bb = Wbf + (size_t)(n0 + rowA) * 512 + kcol;

#define STAGE(buf, kk) { \
    _Pragma("unroll") \
    for (int r = 0; r < 2; ++r) { \
        int rb = (r * 4 + wv) * 16; \
        gload_lds16(Ab + (size_t)rb * 512 + (kk), &aT[buf][rb * 32]); \
        gload_lds16(Bb + (size_t)rb * 512 + (kk), &bT[buf][rb * 32]); \
    } }

    STAGE(0, 0)
    __syncthreads();
    int cur = 0;
    for (int t = 0; t < 16; ++t) {
        if (t < 15) STAGE(cur ^ 1, (t + 1) * 32)
        bf16x8 af[4], bfr[4];
        #pragma unroll
        for (int i = 0; i < 4; ++i) {
            af[i]  = *(const bf16x8*)(&aT[cur][(wm * 64 + i * 16 + l15) * 32 + g4 * 8]);
            bfr[i] = *(const bf16x8*)(&bT[cur][(wn * 64 + i * 16 + l15) * 32 + g4 * 8]);
        }
        #pragma unroll
        for (int i = 0; i < 4; ++i)
            #pragma unroll
            for (int j = 0; j < 4; ++j)
                acc[i][j] = MFMA16(af[i], bfr[j], acc[i][j]);
        __syncthreads();   // drains vmcnt(0): stage(t+1) landed; lgkm done pre-MFMA
        cur ^= 1;
    }
#undef STAGE

    #pragma unroll
    for (int j = 0; j < 4; ++j) {
        int col = n0 + wn * 64 + j * 16 + l15;
        float bi = bias[col];
        #pragma unroll
        for (int i = 0; i < 4; ++i) {
            size_t rowb = m0 + wm * 64 + i * 16 + g4 * 4;
            #pragma unroll
            for (int r = 0; r < 4; ++r)
                Cbf[(rowb + r) * (size_t)Nn + col] = f2bf(acc[i][j][r] + bi);
        }
    }
}

// ---------------------------------------------------------------------------
// K3: attention per (n, head). 2 waves/block, 1 wave = 1 (n,head).
// ---------------------------------------------------------------------------
__global__ __launch_bounds__(128) void k_attn(
    const ushort* __restrict__ C1, const ushort* __restrict__ rpk_g,
    const ushort* __restrict__ rpvT_g, ushort* __restrict__ O) {
    __shared__ ushort rpk_s[32 * 64];    // [d][c]
    __shared__ ushort rpvT_s[64 * 32];   // [c][d]
    __shared__ ushort q_s[2][16 * 64];
    __shared__ ushort k_s[2][16 * 64];
    __shared__ ushort v2_s[2][64 * 40];  // [c][t] stride-40 padded
    __shared__ ushort wbf_s[2][16 * 32];
    __shared__ ushort w2_s[2][16 * 32];
    __shared__ float  pa_s[2][32 * 17];

    int tid = threadIdx.x, lane = tid & 63, wv = tid >> 6;
    *(uint4*)(&rpk_s[tid * 16])      = *(const uint4*)(rpk_g + tid * 16);
    *(uint4*)(&rpk_s[tid * 16 + 8])  = *(const uint4*)(rpk_g + tid * 16 + 8);
    *(uint4*)(&rpvT_s[tid * 16])     = *(const uint4*)(rpvT_g + tid * 16);
    *(uint4*)(&rpvT_s[tid * 16 + 8]) = *(const uint4*)(rpvT_g + tid * 16 + 8);
    __syncthreads();

    int bh = blockIdx.x * 2 + wv;
    int n = bh >> 3, head = bh & 7;
    const ushort* base = C1 + (size_t)n * 16 * 1536 + head * 64;
    ushort* qp = q_s[wv]; ushort* kp = k_s[wv]; ushort* vp = v2_s[wv];
    int t8 = lane >> 3, c8 = (lane & 7) * 8;
    #pragma unroll
    for (int p = 0; p < 2; ++p) {
        int t = p * 8 + t8;
        const ushort* rb = base + (size_t)t * 1536;
        *(uint4*)(&qp[t * 64 + c8]) = *(const uint4*)(rb + c8);
        *(uint4*)(&kp[t * 64 + c8]) = *(const uint4*)(rb + 512 + c8);
        uint4 vvv = *(const uint4*)(rb + 1024 + c8);
        const ushort* vu = (const ushort*)&vvv;
        #pragma unroll
        for (int qq = 0; qq < 8; ++qq) vp[(c8 + qq) * 40 + t] = vu[qq];
    }
    { uint4 z = {0, 0, 0, 0};
      *(uint4*)(&vp[lane * 40 + 16]) = z;
      *(uint4*)(&vp[lane * 40 + 24]) = z; }

    int l15 = lane & 15, g4 = lane >> 4;
    bf16x8 qf0 = *(const bf16x8*)(&qp[l15 * 64 + g4 * 8]);
    bf16x8 qf1 = *(const bf16x8*)(&qp[l15 * 64 + 32 + g4 * 8]);
    bf16x8 kf0 = *(const bf16x8*)(&kp[l15 * 64 + g4 * 8]);
    bf16x8 kf1 = *(const bf16x8*)(&kp[l15 * 64 + 32 + g4 * 8]);
    f32x4 zero = {0.f, 0.f, 0.f, 0.f};
    f32x4 wc = MFMA16(qf0, kf0, zero);
    wc = MFMA16(qf1, kf1, wc);
    f32x4 P0, P1;
    {
        bf16x8 rk;
        rk = *(const bf16x8*)(&rpk_s[l15 * 64 + g4 * 8]);             P0 = MFMA16(rk, qf0, zero);
        rk = *(const bf16x8*)(&rpk_s[l15 * 64 + 32 + g4 * 8]);        P0 = MFMA16(rk, qf1, P0);
        rk = *(const bf16x8*)(&rpk_s[(16 + l15) * 64 + g4 * 8]);      P1 = MFMA16(rk, qf0, zero);
        rk = *(const bf16x8*)(&rpk_s[(16 + l15) * 64 + 32 + g4 * 8]); P1 = MFMA16(rk, qf1, P1);
    }
    float* pa = pa_s[wv];
    #pragma unroll
    for (int r = 0; r < 4; ++r) {
        pa[(g4 * 4 + r) * 17 + l15] = P0[r];
        pa[(16 + g4 * 4 + r) * 17 + l15] = P1[r];
    }
    ushort* wb = wbf_s[wv];
    #pragma unroll
    for (int r = 0; r < 4; ++r) {
        int i = g4 * 4 + r;
        float sc = 0.125f * wc[r] + 0.35355339059327373f * pa[(i - l15 + 15) * 17 + l15];
        float mx = sc;
        mx = fmaxf(mx, __shfl_xor(mx, 1));
        mx = fmaxf(mx, __shfl_xor(mx, 2));
        mx = fmaxf(mx, __shfl_xor(mx, 4));
        mx = fmaxf(mx, __shfl_xor(mx, 8));
        float e = __expf(sc - mx);
        float sm = e;
        sm += __shfl_xor(sm, 1); sm += __shfl_xor(sm, 2);
        sm += __shfl_xor(sm, 4); sm += __shfl_xor(sm, 8);
        float p = e / sm;
        wb[i * 32 + l15] = f2bf(p);
        wb[i * 32 + 16 + l15] = 0;
    }
    ushort* w2 = w2_s[wv];
    #pragma unroll
    for (int q = 0; q < 8; ++q) {
        int e = lane * 8 + q;
        int i = e >> 5, d = e & 31;
        int j = i + d - 15;
        ushort val = 0;
        if (d < 31 && j >= 0 && j < 16) val = wb[i * 32 + j];
        w2[e] = val;
    }
    bf16x8 wfr = *(const bf16x8*)(&wb[l15 * 32 + g4 * 8]);
    bf16x8 w2f = *(const bf16x8*)(&w2[l15 * 32 + g4 * 8]);
    ushort* ob = O + (size_t)n * 16 * 512 + head * 64;
    #pragma unroll
    for (int cj = 0; cj < 4; ++cj) {
        bf16x8 vf  = *(const bf16x8*)(&vp[(cj * 16 + l15) * 40 + g4 * 8]);
        bf16x8 rvf = *(const bf16x8*)(&rpvT_s[(cj * 16 + l15) * 32 + g4 * 8]);
        f32x4 av = MFMA16(wfr, vf, zero);
        av = MFMA16(w2f, rvf, av);
        #pragma unroll
        for (int r = 0; r < 4; ++r)
            ob[(size_t)(g4 * 4 + r) * 512 + cj * 16 + l15] = f2bf(av[r]);
    }
}

// ---------------------------------------------------------------------------
// K5: out[b,c,t,hw] = x + C2[(b*1024+hw)*16+t][c]
// tile: (b, 32 hw, 16 c, all 16 t). C2 reads fully sequential; XOR-swizzled
// LDS transpose (uint-granular); writes 128B-contiguous.
// ---------------------------------------------------------------------------
__global__ __launch_bounds__(256) void k_out(
    const ushort* __restrict__ C2, const float* __restrict__ x,
    float* __restrict__ out) {
    __shared__ uint tw[32 * 16 * 8];   // [hw][t][8 uint] 16KB
    int tid = threadIdx.x;
    int idx = blockIdx.x;
    int cb = idx & 31, hwb = (idx >> 5) & 31, b = idx >> 10;
    int c0 = cb * 16, hw0 = hwb * 32;
    size_t mbase = ((size_t)(b * 1024 + hw0)) * 16;
    #pragma unroll
    for (int it = 0; it < 4; ++it) {
        int flat = it * 256 + tid;
        int row = flat >> 1, cc8 = (flat & 1) * 8;   // row = hw*16+t
        int hw = row >> 4, t = row & 15;
        uint4 v = *(const uint4*)(C2 + (mbase + row) * 512 + c0 + cc8);
        uint wbase = hw * 128 + t * 8;
        uint s = hw & 7;
        int j0 = cc8 >> 1;
        tw[wbase + ((j0 + 0) ^ s)] = v.x;
        tw[wbase + ((j0 + 1) ^ s)] = v.y;
        tw[wbase + ((j0 + 2) ^ s)] = v.z;
        tw[wbase + ((j0 + 3) ^ s)] = v.w;
    }
    __syncthreads();
    #pragma unroll
    for (int it = 0; it < 32; ++it) {
        int flat = it * 256 + tid;
        int hw = flat & 31, ct = flat >> 5;          // ct in [it*8, it*8+8)
        int t = ct & 15, c = ct >> 4;
        uint word = tw[hw * 128 + t * 8 + (((unsigned)c >> 1) ^ (unsigned)(hw & 7))];
        ushort u = (c & 1) ? (ushort)(word >> 16) : (ushort)(word & 0xffff);
        size_t oi = ((size_t)(b * 512 + c0 + c) * 16 + t) * 1024 + hw0 + hw;
        out[oi] = x[oi] + bf2f(u);
    }
}

// ---------------------------------------------------------------------------
extern "C" void kernel_launch(void* const* d_in, const int* in_sizes, int n_in,
                              void* d_out, int out_size, void* d_ws, size_t ws_size,
                              hipStream_t stream) {
    const float* x      = (const float*)d_in[0];
    const float* gamma  = (const float*)d_in[1];
    const float* beta   = (const float*)d_in[2];
    const float* w_qkv  = (const float*)d_in[3];
    const float* b_qkv  = (const float*)d_in[4];
    const float* rp_k   = (const float*)d_in[5];
    const float* rp_v   = (const float*)d_in[6];
    const float* w_proj = (const float*)d_in[7];
    const float* b_proj = (const float*)d_in[8];
    float* out = (float*)d_out;

    ushort* A  = (ushort*)d_ws;                       // 64 MB
    ushort* C1 = A + (size_t)32 * 1024 * 1024;        // 192 MB, later C2
    ushort* C2 = C1;
    ushort* Wq = (ushort*)d_out;                      // scratch in d_out
    ushort* Wp = Wq + 786432;
    ushort* rpk_g  = Wq + 1048576;
    ushort* rpvT_g = rpk_g + 2048;

    k_convw<<<dim3(1025), dim3(256), 0, stream>>>(w_qkv, w_proj, rp_k, rp_v, Wq);
    k_groupnorm<<<dim3(64, 32), dim3(256), 0, stream>>>(x, gamma, beta, A);
    k_gemm<<<dim3(6144), dim3(256), 0, stream>>>(A, Wq, b_qkv, C1, 1536, 12, 64);
    k_attn<<<dim3(16384), dim3(128), 0, stream>>>(C1, rpk_g, rpvT_g, A);
    k_gemm<<<dim3(2048), dim3(256), 0, stream>>>(A, Wp, b_proj, C2, 512, 4, 64);
    k_out<<<dim3(4096), dim3(256), 0, stream>>>(C2, x, out);
}